// Round 9
// baseline (717.486 us; speedup 1.0000x reference)
//
#include <hip/hip_runtime.h>
#include <hip/hip_cooperative_groups.h>
#include <stdint.h>

namespace cg = cooperative_groups;

#define IN1 16
#define HIDC 10
#define OUT3 16
#define NTYPES 25
#define MAXB 8
#define HSTR 12   // padded row stride (floats) for h1/h2: 48B, 16B-aligned rows

#define D1 (IN1 * HIDC)    // 160
#define D2 (HIDC * HIDC)   // 100
#define D3 (HIDC * OUT3)   // 160

// =====================================================================
// Megakernel argument block
// =====================================================================
struct MArgs {
  const float* x; const float2* ef;
  const int *et, *esrc, *edst, *ctype, *bids;
  const float *emb1,*wh1,*bh1,*wg1,*bg1,*root1,*bias1;
  const float *emb2,*wh2,*bh2,*wg2,*bg2,*root2,*bias2;
  const float *emb3,*wh3,*bh3,*wg3,*bg3,*root3,*bias3;
  int4* edges; int *deg,*pos,*row_ptr,*bsum,*ctrs;
  float4 *P1,*P2,*P3;
  float *h1,*h2,*psum,*pcnt,*out;
  int N,E,B;
};

// ---------------------------------------------------------------------
// per-layer phase: load P into LDS, dynamic wave work-queue over 8-node
// pops (2x 4-node tiles), R8-verbatim inner loop (broadcast ds_read_b128
// of packed {P0,P1,P2} + 4 VALU per (i,oc)).
// ---------------------------------------------------------------------
template<int IN_C, int O, int XS, bool POOL>
__device__ __forceinline__ void layer_phase(
    const MArgs& a, const float* __restrict__ xin,
    const float4* __restrict__ Pg,
    const float* __restrict__ root, const float* __restrict__ bias,
    float* __restrict__ hout, int* __restrict__ ctr,
    float4* s_P, float* s_psum, float* s_pcnt)
{
  constexpr int D = IN_C * O;
  constexpr int TSTR = D + 1;
  const int tid = threadIdx.x;
  for (int k = tid; k < NTYPES * D; k += 512) {
    int t = k / D, j = k - t * D;
    s_P[t * TSTR + j] = Pg[k];
  }
  if (POOL) {
    for (int i = tid; i < MAXB * 16; i += 512) s_psum[i] = 0.f;
    for (int i = tid; i < MAXB; i += 512) s_pcnt[i] = 0.f;
  }
  __syncthreads();

  const int o = tid & 15;
  const int sub = (tid >> 4) & 3;
  const int oc = (O == 16) ? o : ((o < O) ? o : 0);
  const int nT = (a.N + 3) >> 2;          // 4-node tiles
  const int nPop = (nT + 1) >> 1;         // 2 tiles per pop

  for (;;) {
    int p = 0;
    if ((tid & 63) == 0) p = atomicAdd(ctr, 1);
    p = __shfl(p, 0);
    if (p >= nPop) break;
    #pragma unroll
    for (int s2 = 0; s2 < 2; ++s2) {
      int tile = p * 2 + s2;
      if (tile >= nT) break;
      int n = tile * 4 + sub;
      float acc = 0.f;
      int start = 0, end = 0;
      if (n < a.N) { start = a.row_ptr[n]; end = a.row_ptr[n + 1]; }
      for (int e = start; e < end; ++e) {
        int4 r = a.edges[e];
        float f0 = __int_as_float(r.z), f1 = __int_as_float(r.w);
        const float4* __restrict__ pb = s_P + r.y * TSTR + oc;
        const float* __restrict__ xr = xin + (size_t)r.x * XS;
        #pragma unroll
        for (int q = 0; q < IN_C / 4; ++q) {
          float4 xq = ((const float4*)xr)[q];
          float4 p0 = pb[(4 * q + 0) * O];
          float4 p1 = pb[(4 * q + 1) * O];
          float4 p2 = pb[(4 * q + 2) * O];
          float4 p3 = pb[(4 * q + 3) * O];
          acc = fmaf(xq.x, fmaxf(fmaf(f0, p0.x, fmaf(f1, p0.y, p0.z)), 0.f), acc);
          acc = fmaf(xq.y, fmaxf(fmaf(f0, p1.x, fmaf(f1, p1.y, p1.z)), 0.f), acc);
          acc = fmaf(xq.z, fmaxf(fmaf(f0, p2.x, fmaf(f1, p2.y, p2.z)), 0.f), acc);
          acc = fmaf(xq.w, fmaxf(fmaf(f0, p3.x, fmaf(f1, p3.y, p3.z)), 0.f), acc);
        }
        if constexpr (IN_C % 4 == 2) {
          float2 xq = ((const float2*)xr)[IN_C / 2 - 1];
          float4 p0 = pb[(IN_C - 2) * O];
          float4 p1 = pb[(IN_C - 1) * O];
          acc = fmaf(xq.x, fmaxf(fmaf(f0, p0.x, fmaf(f1, p0.y, p0.z)), 0.f), acc);
          acc = fmaf(xq.y, fmaxf(fmaf(f0, p1.x, fmaf(f1, p1.y, p1.z)), 0.f), acc);
        }
      }
      if (n < a.N && o < O) {
        float inv = 1.0f / fmaxf((float)(end - start), 1.0f);
        float v = fmaf(acc, inv, bias[o]);
        const float* __restrict__ xr = xin + (size_t)n * XS;
        #pragma unroll
        for (int i = 0; i < IN_C; ++i) v = fmaf(xr[i], root[i * O + o], v);
        v = fmaxf(v, 0.f);
        if (!POOL) {
          hout[(size_t)n * HSTR + o] = v;
        } else {
          if (a.ctype[n] == 1) {
            int b = a.bids[n];
            atomicAdd(&s_psum[b * 16 + o], v);
            if (o == 0) atomicAdd(&s_pcnt[b], 1.0f);
          }
        }
      }
    }
  }

  if (POOL) {
    __syncthreads();
    for (int i = tid; i < a.B * 16; i += 512) {
      float v = s_psum[i];
      if (v != 0.f) atomicAdd(&a.psum[i], v);
    }
    for (int i = tid; i < a.B; i += 512) {
      float c = s_pcnt[i];
      if (c != 0.f) atomicAdd(&a.pcnt[i], c);
    }
  }
}

// =====================================================================
// One cooperative megakernel: prep -> hist -> scan -> permute -> L1 ->
// L2 -> L3+pool -> finalize, with grid.sync() between phases.
// =====================================================================
__global__ __launch_bounds__(512) void mega_kernel(MArgs a)
{
  cg::grid_group grid = cg::this_grid();
  __shared__ __align__(16) float4 s_P[NTYPES * (D1 + 1)];  // 64,400 B
  __shared__ float s_psum[MAXB * 16];
  __shared__ float s_pcnt[MAXB];
  __shared__ int s_w[8];

  const int tid = threadIdx.x;
  const int gtid = blockIdx.x * 512 + tid;
  const int gstr = gridDim.x * 512;

  // ---- phase 0: prep P tables + zero deg/psum/pcnt/ctrs ----
  const int nPrep = NTYPES * (D1 + D2 + D3);
  for (int i = gtid; i < nPrep; i += gstr) {
    const float *emb, *wh, *bh, *wg, *bg; float4* P; int D, k;
    if (i < NTYPES * D1) {
      emb = a.emb1; wh = a.wh1; bh = a.bh1; wg = a.wg1; bg = a.bg1;
      P = a.P1; D = D1; k = i;
    } else if (i < NTYPES * (D1 + D2)) {
      emb = a.emb2; wh = a.wh2; bh = a.bh2; wg = a.wg2; bg = a.bg2;
      P = a.P2; D = D2; k = i - NTYPES * D1;
    } else {
      emb = a.emb3; wh = a.wh3; bh = a.bh3; wg = a.wg3; bg = a.bg3;
      P = a.P3; D = D3; k = i - NTYPES * (D1 + D2);
    }
    int j = k - (k / D) * D;
    float e = emb[k];
    float4 p;
    p.x = fmaf(e, wh[j],     wg[j]);
    p.y = fmaf(e, wh[D + j], wg[D + j]);
    p.z = fmaf(e, bh[j],     bg[j]);
    p.w = 0.f;
    P[k] = p;
  }
  for (int i = gtid; i < a.N; i += gstr) a.deg[i] = 0;
  for (int i = gtid; i < a.B * 16; i += gstr) a.psum[i] = 0.f;
  for (int i = gtid; i < a.B; i += gstr) a.pcnt[i] = 0.f;
  if (gtid < 4) a.ctrs[gtid] = 0;
  grid.sync();

  // ---- phase 1: histogram + per-edge rank ----
  for (int e = gtid; e < a.E; e += gstr) a.pos[e] = atomicAdd(&a.deg[a.edst[e]], 1);
  grid.sync();

  // ---- phase 2a: per-1024-chunk local scan ----
  const int chunks = (a.N + 1023) >> 10;
  if (blockIdx.x < chunks) {
    int c = blockIdx.x;
    int idx0 = (c << 10) + tid * 2;
    int vx = (idx0 < a.N) ? a.deg[idx0] : 0;
    int vy = (idx0 + 1 < a.N) ? a.deg[idx0 + 1] : 0;
    int s = vx + vy;
    int x = s;
    int lane = tid & 63, wid = tid >> 6;
    #pragma unroll
    for (int off = 1; off < 64; off <<= 1) {
      int y = __shfl_up(x, off);
      if (lane >= off) x += y;
    }
    if (lane == 63) s_w[wid] = x;
    __syncthreads();
    if (tid < 8) {
      int w = s_w[tid];
      #pragma unroll
      for (int off = 1; off < 8; off <<= 1) {
        int y = __shfl_up(w, off);
        if (tid >= off) w += y;
      }
      s_w[tid] = w;
    }
    __syncthreads();
    int excl = x - s + ((wid > 0) ? s_w[wid - 1] : 0);
    if (idx0 < a.N)     a.row_ptr[idx0]     = excl;
    if (idx0 + 1 < a.N) a.row_ptr[idx0 + 1] = excl + vx;
    if (tid == 511) a.bsum[c] = excl + s;
  }
  grid.sync();
  // ---- phase 2b: scan chunk sums (one wave) ----
  if (blockIdx.x == 0 && tid < 64) {
    int v = (tid < chunks) ? a.bsum[tid] : 0;
    int x = v;
    #pragma unroll
    for (int off = 1; off < 64; off <<= 1) {
      int y = __shfl_up(x, off);
      if (tid >= off) x += y;
    }
    if (tid < chunks) a.bsum[tid] = x - v;
    if (tid == 63) a.row_ptr[a.N] = x;
  }
  grid.sync();
  // ---- phase 2c: add chunk offsets ----
  for (int i = gtid; i < a.N; i += gstr) a.row_ptr[i] += a.bsum[i >> 10];
  grid.sync();

  // ---- phase 3: permute edges into CSR order ----
  for (int e = gtid; e < a.E; e += gstr) {
    int d = a.edst[e];
    int idx = a.row_ptr[d] + a.pos[e];
    float2 f = a.ef[e];
    int4 r;
    r.x = a.esrc[e];
    r.y = a.et[e];
    r.z = __float_as_int(f.x);
    r.w = __float_as_int(f.y);
    a.edges[idx] = r;
  }
  grid.sync();

  // ---- layers ----
  layer_phase<IN1, HIDC, IN1, false>(a, a.x, a.P1, a.root1, a.bias1,
                                     a.h1, a.ctrs + 0, s_P, s_psum, s_pcnt);
  grid.sync();
  layer_phase<HIDC, HIDC, HSTR, false>(a, a.h1, a.P2, a.root2, a.bias2,
                                       a.h2, a.ctrs + 1, s_P, s_psum, s_pcnt);
  grid.sync();
  layer_phase<HIDC, OUT3, HSTR, true>(a, a.h2, a.P3, a.root3, a.bias3,
                                      a.psum, a.ctrs + 2, s_P, s_psum, s_pcnt);
  grid.sync();

  // ---- finalize ----
  if (blockIdx.x == 0 && tid < a.B * OUT3) {
    int b = tid / OUT3;
    a.out[tid] = a.psum[tid] / fmaxf(a.pcnt[b], 1.0f);
  }
}

// =====================================================================
// Fallback path: R8-verbatim multi-kernel pipeline (known 253 us)
// =====================================================================
__global__ __launch_bounds__(256) void zero2_kernel(int* __restrict__ a, int na,
                                                    int* __restrict__ b, int nb) {
  int i = blockIdx.x * blockDim.x + threadIdx.x;
  int s = gridDim.x * blockDim.x;
  for (int j = i; j < na; j += s) a[j] = 0;
  for (int j = i; j < nb; j += s) b[j] = 0;
}

__global__ __launch_bounds__(256) void hist_kernel(const int* __restrict__ edst,
                                                   int* __restrict__ deg,
                                                   int* __restrict__ pos, int E) {
  int e = blockIdx.x * blockDim.x + threadIdx.x;
  if (e < E) pos[e] = atomicAdd(&deg[edst[e]], 1);
}

__global__ __launch_bounds__(256) void scan_part_kernel(const int* __restrict__ deg,
                                                        int* __restrict__ row_ptr,
                                                        int* __restrict__ bsum, int N) {
  __shared__ int wsums[4];
  int tid = threadIdx.x, lane = tid & 63, wid = tid >> 6;
  int idx0 = (blockIdx.x * 256 + tid) * 4;
  int4 v = make_int4(0, 0, 0, 0);
  if (idx0 < N)     v.x = deg[idx0];
  if (idx0 + 1 < N) v.y = deg[idx0 + 1];
  if (idx0 + 2 < N) v.z = deg[idx0 + 2];
  if (idx0 + 3 < N) v.w = deg[idx0 + 3];
  int s = v.x + v.y + v.z + v.w;
  int x = s;
  #pragma unroll
  for (int off = 1; off < 64; off <<= 1) {
    int y = __shfl_up(x, off);
    if (lane >= off) x += y;
  }
  if (lane == 63) wsums[wid] = x;
  __syncthreads();
  int wpre = 0;
  #pragma unroll
  for (int w = 0; w < 4; ++w) if (w < wid) wpre += wsums[w];
  int excl = x - s + wpre;
  if (idx0 < N)     row_ptr[idx0]     = excl;
  if (idx0 + 1 < N) row_ptr[idx0 + 1] = excl + v.x;
  if (idx0 + 2 < N) row_ptr[idx0 + 2] = excl + v.x + v.y;
  if (idx0 + 3 < N) row_ptr[idx0 + 3] = excl + v.x + v.y + v.z;
  if (tid == 255) bsum[blockIdx.x] = excl + s;
}

__global__ __launch_bounds__(64) void scan_bsum_kernel(int* __restrict__ bsum,
                                                       int* __restrict__ row_ptr,
                                                       int G, int N) {
  int tid = threadIdx.x;
  int v = (tid < G) ? bsum[tid] : 0;
  int x = v;
  #pragma unroll
  for (int off = 1; off < 64; off <<= 1) {
    int y = __shfl_up(x, off);
    if (tid >= off) x += y;
  }
  if (tid < G) bsum[tid] = x - v;
  if (tid == 63) row_ptr[N] = x;
}

__global__ __launch_bounds__(256) void scan_add_kernel(int* __restrict__ row_ptr,
                                                       const int* __restrict__ bsum,
                                                       int N) {
  int i = blockIdx.x * blockDim.x + threadIdx.x;
  if (i < N) row_ptr[i] += bsum[i >> 10];
}

__global__ __launch_bounds__(256) void permute_kernel(
    const int* __restrict__ edst, const int* __restrict__ esrc,
    const int* __restrict__ et, const float2* __restrict__ ef,
    const int* __restrict__ row_ptr, const int* __restrict__ pos,
    int4* __restrict__ edges, int E) {
  int e = blockIdx.x * blockDim.x + threadIdx.x;
  if (e >= E) return;
  int d = edst[e];
  int idx = row_ptr[d] + pos[e];
  float2 f = ef[e];
  int4 r;
  r.x = esrc[e];
  r.y = et[e];
  r.z = __float_as_int(f.x);
  r.w = __float_as_int(f.y);
  edges[idx] = r;
}

__global__ __launch_bounds__(256) void prep_kernel(
    const float* __restrict__ emb1, const float* __restrict__ wh1,
    const float* __restrict__ bh1, const float* __restrict__ wg1,
    const float* __restrict__ bg1,
    const float* __restrict__ emb2, const float* __restrict__ wh2,
    const float* __restrict__ bh2, const float* __restrict__ wg2,
    const float* __restrict__ bg2,
    const float* __restrict__ emb3, const float* __restrict__ wh3,
    const float* __restrict__ bh3, const float* __restrict__ wg3,
    const float* __restrict__ bg3,
    float4* __restrict__ P1, float4* __restrict__ P2, float4* __restrict__ P3)
{
  int i = blockIdx.x * 256 + threadIdx.x;
  const float *emb, *wh, *bh, *wg, *bg;
  float4* P; int D, k;
  if (i < NTYPES * D1) {
    emb = emb1; wh = wh1; bh = bh1; wg = wg1; bg = bg1; P = P1; D = D1; k = i;
  } else if (i < NTYPES * (D1 + D2)) {
    emb = emb2; wh = wh2; bh = bh2; wg = wg2; bg = bg2; P = P2; D = D2;
    k = i - NTYPES * D1;
  } else if (i < NTYPES * (D1 + D2 + D3)) {
    emb = emb3; wh = wh3; bh = bh3; wg = wg3; bg = bg3; P = P3; D = D3;
    k = i - NTYPES * (D1 + D2);
  } else return;
  int j = k - (k / D) * D;
  float e = emb[k];
  float4 p;
  p.x = fmaf(e, wh[j],     wg[j]);
  p.y = fmaf(e, wh[D + j], wg[D + j]);
  p.z = fmaf(e, bh[j],     bg[j]);
  p.w = 0.f;
  P[k] = p;
}

template<int IN_C, int O, int XS, bool POOL, int BS>
__global__ __launch_bounds__(BS) void layer_kernel(
    const float* __restrict__ xin, const int4* __restrict__ edges,
    const int* __restrict__ row_ptr, const float4* __restrict__ Pg,
    const float* __restrict__ root, const float* __restrict__ bias,
    float* __restrict__ hout, const int* __restrict__ ctype,
    const int* __restrict__ bids, float* __restrict__ pcnt, int N, int B)
{
  constexpr int D = IN_C * O;
  constexpr int TSTR = D + 1;
  constexpr int NPB = BS / 16;
  __shared__ float4 s_P[NTYPES * TSTR];
  __shared__ float s_psum[POOL ? (MAXB * 16) : 1];
  __shared__ float s_pcnt[POOL ? MAXB : 1];

  int tid = threadIdx.x;
  for (int k = tid; k < NTYPES * D; k += BS) {
    int t = k / D, j = k - t * D;
    s_P[t * TSTR + j] = Pg[k];
  }
  if (POOL) {
    for (int i = tid; i < MAXB * 16; i += BS) s_psum[i] = 0.f;
    for (int i = tid; i < MAXB; i += BS) s_pcnt[i] = 0.f;
  }
  __syncthreads();

  int nl = tid >> 4;
  int o = tid & 15;
  int oc = (O == 16) ? o : ((o < O) ? o : 0);
  int n = blockIdx.x * NPB + nl;

  float acc = 0.f;
  int start = 0, end = 0;
  if (n < N) { start = row_ptr[n]; end = row_ptr[n + 1]; }
  for (int e = start; e < end; ++e) {
    int4 r = edges[e];
    float f0 = __int_as_float(r.z), f1 = __int_as_float(r.w);
    const float4* __restrict__ pb = s_P + r.y * TSTR + oc;
    const float* __restrict__ xr = xin + (size_t)r.x * XS;
    #pragma unroll
    for (int q = 0; q < IN_C / 4; ++q) {
      float4 xq = ((const float4*)xr)[q];
      float4 p0 = pb[(4 * q + 0) * O];
      float4 p1 = pb[(4 * q + 1) * O];
      float4 p2 = pb[(4 * q + 2) * O];
      float4 p3 = pb[(4 * q + 3) * O];
      acc = fmaf(xq.x, fmaxf(fmaf(f0, p0.x, fmaf(f1, p0.y, p0.z)), 0.f), acc);
      acc = fmaf(xq.y, fmaxf(fmaf(f0, p1.x, fmaf(f1, p1.y, p1.z)), 0.f), acc);
      acc = fmaf(xq.z, fmaxf(fmaf(f0, p2.x, fmaf(f1, p2.y, p2.z)), 0.f), acc);
      acc = fmaf(xq.w, fmaxf(fmaf(f0, p3.x, fmaf(f1, p3.y, p3.z)), 0.f), acc);
    }
    if constexpr (IN_C % 4 == 2) {
      float2 xq = ((const float2*)xr)[IN_C / 2 - 1];
      float4 p0 = pb[(IN_C - 2) * O];
      float4 p1 = pb[(IN_C - 1) * O];
      acc = fmaf(xq.x, fmaxf(fmaf(f0, p0.x, fmaf(f1, p0.y, p0.z)), 0.f), acc);
      acc = fmaf(xq.y, fmaxf(fmaf(f0, p1.x, fmaf(f1, p1.y, p1.z)), 0.f), acc);
    }
  }

  if (n < N && o < O) {
    float inv = 1.0f / fmaxf((float)(end - start), 1.0f);
    float v = fmaf(acc, inv, bias[o]);
    const float* __restrict__ xr = xin + (size_t)n * XS;
    #pragma unroll
    for (int i = 0; i < IN_C; ++i) v = fmaf(xr[i], root[i * O + o], v);
    v = fmaxf(v, 0.f);
    if (!POOL) {
      hout[(size_t)n * HSTR + o] = v;
    } else {
      if (ctype[n] == 1) {
        int b = bids[n];
        atomicAdd(&s_psum[b * 16 + o], v);
        if (o == 0) atomicAdd(&s_pcnt[b], 1.0f);
      }
    }
  }

  if (POOL) {
    __syncthreads();
    for (int i = tid; i < B * 16; i += BS) {
      float v = s_psum[i];
      if (v != 0.f) atomicAdd(&hout[i], v);
    }
    for (int i = tid; i < B; i += BS) {
      float c = s_pcnt[i];
      if (c != 0.f) atomicAdd(&pcnt[i], c);
    }
  }
}

__global__ __launch_bounds__(256) void finalize_kernel(
    const float* __restrict__ psum, const float* __restrict__ pcnt,
    float* __restrict__ out, int B) {
  int i = blockIdx.x * blockDim.x + threadIdx.x;
  if (i >= B * OUT3) return;
  int b = i / OUT3;
  out[i] = psum[i] / fmaxf(pcnt[b], 1.0f);
}

// =====================================================================
// launch
// =====================================================================
extern "C" void kernel_launch(void* const* d_in, const int* in_sizes, int n_in,
                              void* d_out, int out_size, void* d_ws, size_t ws_size,
                              hipStream_t stream)
{
  const float* x     = (const float*)d_in[0];
  const float* ef    = (const float*)d_in[1];
  const int*   et    = (const int*)d_in[2];
  const int*   esrc  = (const int*)d_in[3];
  const int*   edst  = (const int*)d_in[4];
  const int*   ctype = (const int*)d_in[5];
  const int*   bids  = (const int*)d_in[6];
  const float* emb1 = (const float*)d_in[8];
  const float* wh1  = (const float*)d_in[9];
  const float* bh1  = (const float*)d_in[10];
  const float* wg1  = (const float*)d_in[11];
  const float* bg1  = (const float*)d_in[12];
  const float* root1= (const float*)d_in[13];
  const float* bias1= (const float*)d_in[14];
  const float* emb2 = (const float*)d_in[15];
  const float* wh2  = (const float*)d_in[16];
  const float* bh2  = (const float*)d_in[17];
  const float* wg2  = (const float*)d_in[18];
  const float* bg2  = (const float*)d_in[19];
  const float* root2= (const float*)d_in[20];
  const float* bias2= (const float*)d_in[21];
  const float* emb3 = (const float*)d_in[22];
  const float* wh3  = (const float*)d_in[23];
  const float* bh3  = (const float*)d_in[24];
  const float* wg3  = (const float*)d_in[25];
  const float* bg3  = (const float*)d_in[26];
  const float* root3= (const float*)d_in[27];
  const float* bias3= (const float*)d_in[28];

  const int N = in_sizes[0] / IN1;
  const int E = in_sizes[2];
  const int B = out_size / OUT3;

  // workspace layout (16B-aligned sections)
  int4* edges   = (int4*)d_ws;                       // E recs
  int*  deg     = (int*)(edges + E);                 // N
  int*  pos     = deg + N;                           // E
  int*  row_ptr = pos + E;                           // N+1
  int*  bsum    = row_ptr + (N + 1);                 // <=64
  int*  ctrs    = bsum + 64;                         // 4 queue counters
  uintptr_t pp  = ((uintptr_t)(ctrs + 4) + 15) & ~(uintptr_t)15;
  float4* P1    = (float4*)pp;                       // 25*D1
  float4* P2    = P1 + NTYPES * D1;                  // 25*D2
  float4* P3    = P2 + NTYPES * D2;                  // 25*D3
  float* h1     = (float*)(P3 + NTYPES * D3);        // N*HSTR
  float* h2     = h1 + (size_t)N * HSTR;             // N*HSTR
  float* psum   = h2 + (size_t)N * HSTR;             // B*16
  float* pcnt   = psum + (size_t)B * 16;             // B

  // --- try the cooperative megakernel (one launch; ~110us of gaps removed) ---
  static int coopBlocks = -2;
  if (coopBlocks == -2) {
    int nb = 0;
    hipError_t qe = hipOccupancyMaxActiveBlocksPerMultiprocessor(
        &nb, mega_kernel, 512, 0);
    coopBlocks = (qe == hipSuccess && nb >= 1) ? nb * 256 : -1;
  }

  bool done = false;
  if (coopBlocks > 0) {
    MArgs ma;
    ma.x = x; ma.ef = (const float2*)ef;
    ma.et = et; ma.esrc = esrc; ma.edst = edst; ma.ctype = ctype; ma.bids = bids;
    ma.emb1=emb1; ma.wh1=wh1; ma.bh1=bh1; ma.wg1=wg1; ma.bg1=bg1; ma.root1=root1; ma.bias1=bias1;
    ma.emb2=emb2; ma.wh2=wh2; ma.bh2=bh2; ma.wg2=wg2; ma.bg2=bg2; ma.root2=root2; ma.bias2=bias2;
    ma.emb3=emb3; ma.wh3=wh3; ma.bh3=bh3; ma.wg3=wg3; ma.bg3=bg3; ma.root3=root3; ma.bias3=bias3;
    ma.edges = edges; ma.deg = deg; ma.pos = pos; ma.row_ptr = row_ptr;
    ma.bsum = bsum; ma.ctrs = ctrs;
    ma.P1 = P1; ma.P2 = P2; ma.P3 = P3;
    ma.h1 = h1; ma.h2 = h2; ma.psum = psum; ma.pcnt = pcnt;
    ma.out = (float*)d_out;
    ma.N = N; ma.E = E; ma.B = B;
    void* kargs[] = { &ma };
    hipError_t le = hipLaunchCooperativeKernel(
        (void*)mega_kernel, dim3(coopBlocks), dim3(512), kargs, 0, stream);
    if (le == hipSuccess) done = true;
  }

  if (!done) {
    // --- fallback: R8-verbatim multi-kernel pipeline ---
    const int nChunk = (N + 1023) / 1024;
    const int nPrep  = NTYPES * (D1 + D2 + D3);

    zero2_kernel<<<128, 256, 0, stream>>>(deg, N, (int*)psum, B * 16 + B);
    prep_kernel<<<(nPrep + 255) / 256, 256, 0, stream>>>(
        emb1, wh1, bh1, wg1, bg1, emb2, wh2, bh2, wg2, bg2,
        emb3, wh3, bh3, wg3, bg3, P1, P2, P3);
    hist_kernel<<<(E + 255) / 256, 256, 0, stream>>>(edst, deg, pos, E);
    scan_part_kernel<<<nChunk, 256, 0, stream>>>(deg, row_ptr, bsum, N);
    scan_bsum_kernel<<<1, 64, 0, stream>>>(bsum, row_ptr, nChunk, N);
    scan_add_kernel<<<(N + 255) / 256, 256, 0, stream>>>(row_ptr, bsum, N);
    permute_kernel<<<(E + 255) / 256, 256, 0, stream>>>(
        edst, esrc, et, (const float2*)ef, row_ptr, pos, edges, E);

    const int g512 = (N + 31) / 32;
    layer_kernel<IN1, HIDC, IN1, false, 512><<<g512, 512, 0, stream>>>(
        x, edges, row_ptr, P1, root1, bias1,
        h1, nullptr, nullptr, nullptr, N, B);
    layer_kernel<HIDC, HIDC, HSTR, false, 512><<<g512, 512, 0, stream>>>(
        h1, edges, row_ptr, P2, root2, bias2,
        h2, nullptr, nullptr, nullptr, N, B);

    const int g1024 = (N + 63) / 64;
    layer_kernel<HIDC, OUT3, HSTR, true, 1024><<<g1024, 1024, 0, stream>>>(
        h2, edges, row_ptr, P3, root3, bias3,
        psum, ctype, bids, pcnt, N, B);

    finalize_kernel<<<1, 256, 0, stream>>>(psum, pcnt, (float*)d_out, B);
  }
}

// Round 10
// 493.573 us; speedup vs baseline: 1.4537x; 1.4537x over previous
//
#include <hip/hip_runtime.h>
#include <stdint.h>

#define IN1 16
#define HIDC 10
#define OUT3 16
#define NTYPES 25
#define MAXB 8
#define HSTR 12   // padded row stride (floats) for h1/h2: 48B, 16B-aligned rows

#define D1 (IN1 * HIDC)    // 160
#define D2 (HIDC * HIDC)   // 100
#define D3 (HIDC * OUT3)   // 160

// ---------------- init: prep P tables + zero deg/psum/pcnt/done --------------
// w_edge = relu(f0*P0 + f1*P1 + P2); P0=emb*wh0+wg0, P1=emb*wh1+wg1, P2=emb*bh+bg
__global__ __launch_bounds__(256) void init_kernel(
    const float* __restrict__ emb1, const float* __restrict__ wh1,
    const float* __restrict__ bh1, const float* __restrict__ wg1,
    const float* __restrict__ bg1,
    const float* __restrict__ emb2, const float* __restrict__ wh2,
    const float* __restrict__ bh2, const float* __restrict__ wg2,
    const float* __restrict__ bg2,
    const float* __restrict__ emb3, const float* __restrict__ wh3,
    const float* __restrict__ bh3, const float* __restrict__ wg3,
    const float* __restrict__ bg3,
    float4* __restrict__ P1, float4* __restrict__ P2, float4* __restrict__ P3,
    int* __restrict__ deg, int N,
    float* __restrict__ psum, float* __restrict__ pcnt,
    int* __restrict__ done, int B)
{
  int gtid = blockIdx.x * 256 + threadIdx.x;
  int gstr = gridDim.x * 256;
  const int nPrep = NTYPES * (D1 + D2 + D3);
  for (int i = gtid; i < nPrep; i += gstr) {
    const float *emb, *wh, *bh, *wg, *bg; float4* P; int D, k;
    if (i < NTYPES * D1) {
      emb = emb1; wh = wh1; bh = bh1; wg = wg1; bg = bg1; P = P1; D = D1; k = i;
    } else if (i < NTYPES * (D1 + D2)) {
      emb = emb2; wh = wh2; bh = bh2; wg = wg2; bg = bg2; P = P2; D = D2;
      k = i - NTYPES * D1;
    } else {
      emb = emb3; wh = wh3; bh = bh3; wg = wg3; bg = bg3; P = P3; D = D3;
      k = i - NTYPES * (D1 + D2);
    }
    int j = k - (k / D) * D;
    float e = emb[k];
    float4 p;
    p.x = fmaf(e, wh[j],     wg[j]);
    p.y = fmaf(e, wh[D + j], wg[D + j]);
    p.z = fmaf(e, bh[j],     bg[j]);
    p.w = 0.f;
    P[k] = p;
  }
  for (int i = gtid; i < N; i += gstr) deg[i] = 0;
  for (int i = gtid; i < B * 16; i += gstr) psum[i] = 0.f;
  for (int i = gtid; i < B; i += gstr) pcnt[i] = 0.f;
  if (gtid == 0) *done = 0;
}

// ---------------- histogram + within-bucket rank (1 atomic per edge) ----------
__global__ __launch_bounds__(256) void hist_kernel(const int* __restrict__ edst,
                                                   int* __restrict__ deg,
                                                   int* __restrict__ pos, int E) {
  int e = blockIdx.x * blockDim.x + threadIdx.x;
  if (e < E) pos[e] = atomicAdd(&deg[edst[e]], 1);
}

// ---------------- per-1024-chunk local scan + chunk sum ----------------------
__global__ __launch_bounds__(256) void scan_part_kernel(const int* __restrict__ deg,
                                                        int* __restrict__ row_ptr,
                                                        int* __restrict__ bsum, int N) {
  __shared__ int wsums[4];
  int tid = threadIdx.x, lane = tid & 63, wid = tid >> 6;
  int idx0 = (blockIdx.x * 256 + tid) * 4;
  int4 v = make_int4(0, 0, 0, 0);
  if (idx0 < N)     v.x = deg[idx0];
  if (idx0 + 1 < N) v.y = deg[idx0 + 1];
  if (idx0 + 2 < N) v.z = deg[idx0 + 2];
  if (idx0 + 3 < N) v.w = deg[idx0 + 3];
  int s = v.x + v.y + v.z + v.w;
  int x = s;
  #pragma unroll
  for (int off = 1; off < 64; off <<= 1) {
    int y = __shfl_up(x, off);
    if (lane >= off) x += y;
  }
  if (lane == 63) wsums[wid] = x;
  __syncthreads();
  int wpre = 0;
  #pragma unroll
  for (int w = 0; w < 4; ++w) if (w < wid) wpre += wsums[w];
  int excl = x - s + wpre;
  if (idx0 < N)     row_ptr[idx0]     = excl;
  if (idx0 + 1 < N) row_ptr[idx0 + 1] = excl + v.x;
  if (idx0 + 2 < N) row_ptr[idx0 + 2] = excl + v.x + v.y;
  if (idx0 + 3 < N) row_ptr[idx0 + 3] = excl + v.x + v.y + v.z;
  if (tid == 255) bsum[blockIdx.x] = excl + s;
}

// ---------------- fused chunk-offset scan + add (chunks <= 64) ----------------
// Each block redundantly reduces bsum[0..c-1] in one wave (<=64 ints) -- cheaper
// than a separate single-wave kernel + its launch gap.
__global__ __launch_bounds__(256) void scan_add2_kernel(int* __restrict__ row_ptr,
                                                        const int* __restrict__ bsum,
                                                        int N, int chunks) {
  __shared__ int s_off;
  int c = blockIdx.x, tid = threadIdx.x;
  if (tid < 64) {
    int v = (tid < c) ? bsum[tid] : 0;
    #pragma unroll
    for (int off = 32; off >= 1; off >>= 1) v += __shfl_xor(v, off);
    if (tid == 0) s_off = v;
  }
  __syncthreads();
  int off = s_off;
  int base = c * 1024 + tid * 4;
  #pragma unroll
  for (int j = 0; j < 4; ++j) {
    int idx = base + j;
    if (idx < N) row_ptr[idx] += off;
  }
  if (c == chunks - 1 && tid == 0) row_ptr[N] = off + bsum[c];
}

// ---------------- scatter edges into CSR order (plain stores) ----------------
__global__ __launch_bounds__(256) void permute_kernel(
    const int* __restrict__ edst, const int* __restrict__ esrc,
    const int* __restrict__ et, const float2* __restrict__ ef,
    const int* __restrict__ row_ptr, const int* __restrict__ pos,
    int4* __restrict__ edges, int E) {
  int e = blockIdx.x * blockDim.x + threadIdx.x;
  if (e >= E) return;
  int d = edst[e];
  int idx = row_ptr[d] + pos[e];
  float2 f = ef[e];
  int4 r;
  r.x = esrc[e];
  r.y = et[e];
  r.z = __float_as_int(f.x);
  r.w = __float_as_int(f.y);
  edges[idx] = r;
}

// ---------------- fused gather layer: msg-agg + mean + root + bias + relu ----
// R8 inner math, but P read DIRECTLY FROM GLOBAL (L2-resident 40-64KB table):
// per (i,oc) one broadcast global_load_dwordx4 (16 consecutive float4s per
// 16-lane group = 256B coalesced).  No s_P -> LDS ~0 -> occupancy VGPR-limited
// (8 waves/SIMD at <=64 VGPR) instead of LDS-limited 1 block/CU.
// POOL variant folds finalize in via device-scope done-counter.
template<int IN_C, int O, int XS, bool POOL, int BS>
__global__ __launch_bounds__(BS, 8) void layer_kernel(
    const float* __restrict__ xin,      // [N, XS]
    const int4* __restrict__ edges,     // CSR by dst: {src, type, f0, f1}
    const int* __restrict__ row_ptr,    // [N+1]
    const float4* __restrict__ Pg,      // [25*D] packed {P0,P1,P2,-}
    const float* __restrict__ root,     // [IN_C, O]
    const float* __restrict__ bias,     // [O]
    float* __restrict__ hout,           // [N, HSTR], or psum[B*16] if POOL
    const int* __restrict__ ctype, const int* __restrict__ bids,
    float* __restrict__ pcnt,           // [B] (POOL only)
    int* __restrict__ done,             // (POOL only)
    float* __restrict__ out,            // [B*16] (POOL only)
    int N, int B)
{
  constexpr int D = IN_C * O;
  constexpr int NPB = BS / 16;
  __shared__ float s_psum[POOL ? (MAXB * 16) : 1];
  __shared__ float s_pcnt[POOL ? MAXB : 1];

  int tid = threadIdx.x;
  if (POOL) {
    for (int i = tid; i < MAXB * 16; i += BS) s_psum[i] = 0.f;
    for (int i = tid; i < MAXB; i += BS) s_pcnt[i] = 0.f;
    __syncthreads();
  }

  int nl = tid >> 4;
  int o = tid & 15;
  int oc = (O == 16) ? o : ((o < O) ? o : 0);
  int n = blockIdx.x * NPB + nl;

  float acc = 0.f;
  int start = 0, end = 0;
  if (n < N) { start = row_ptr[n]; end = row_ptr[n + 1]; }
  for (int e = start; e < end; ++e) {
    int4 r = edges[e];
    float f0 = __int_as_float(r.z), f1 = __int_as_float(r.w);
    const float4* __restrict__ pb = Pg + r.y * D + oc;   // stride O per i
    const float* __restrict__ xr = xin + (size_t)r.x * XS;
    #pragma unroll
    for (int q = 0; q < IN_C / 4; ++q) {
      float4 xq = ((const float4*)xr)[q];
      float4 p0 = pb[(4 * q + 0) * O];
      float4 p1 = pb[(4 * q + 1) * O];
      float4 p2 = pb[(4 * q + 2) * O];
      float4 p3 = pb[(4 * q + 3) * O];
      acc = fmaf(xq.x, fmaxf(fmaf(f0, p0.x, fmaf(f1, p0.y, p0.z)), 0.f), acc);
      acc = fmaf(xq.y, fmaxf(fmaf(f0, p1.x, fmaf(f1, p1.y, p1.z)), 0.f), acc);
      acc = fmaf(xq.z, fmaxf(fmaf(f0, p2.x, fmaf(f1, p2.y, p2.z)), 0.f), acc);
      acc = fmaf(xq.w, fmaxf(fmaf(f0, p3.x, fmaf(f1, p3.y, p3.z)), 0.f), acc);
    }
    if constexpr (IN_C % 4 == 2) {
      float2 xq = ((const float2*)xr)[IN_C / 2 - 1];
      float4 p0 = pb[(IN_C - 2) * O];
      float4 p1 = pb[(IN_C - 1) * O];
      acc = fmaf(xq.x, fmaxf(fmaf(f0, p0.x, fmaf(f1, p0.y, p0.z)), 0.f), acc);
      acc = fmaf(xq.y, fmaxf(fmaf(f0, p1.x, fmaf(f1, p1.y, p1.z)), 0.f), acc);
    }
  }

  if (n < N && o < O) {
    float inv = 1.0f / fmaxf((float)(end - start), 1.0f);
    float v = fmaf(acc, inv, bias[o]);
    const float* __restrict__ xr = xin + (size_t)n * XS;
    #pragma unroll
    for (int i = 0; i < IN_C; ++i) v = fmaf(xr[i], root[i * O + o], v);
    v = fmaxf(v, 0.f);
    if (!POOL) {
      hout[(size_t)n * HSTR + o] = v;
    } else {
      if (ctype[n] == 1) {
        int b = bids[n];
        atomicAdd(&s_psum[b * 16 + o], v);
        if (o == 0) atomicAdd(&s_pcnt[b], 1.0f);
      }
    }
  }

  if (POOL) {
    __syncthreads();
    for (int i = tid; i < B * 16; i += BS) {
      float v = s_psum[i];
      if (v != 0.f) atomicAdd(&hout[i], v);    // hout = psum (global)
    }
    for (int i = tid; i < B; i += BS) {
      float c = s_pcnt[i];
      if (c != 0.f) atomicAdd(&pcnt[i], c);
    }
    // folded finalize: last block to finish divides and writes out
    __threadfence();
    __shared__ int s_last;
    if (tid == 0) s_last = (atomicAdd(done, 1) == (int)gridDim.x - 1) ? 1 : 0;
    __syncthreads();
    if (s_last) {
      for (int i = tid; i < B * 16; i += BS) {
        float ps = __hip_atomic_load(&hout[i], __ATOMIC_RELAXED,
                                     __HIP_MEMORY_SCOPE_AGENT);
        float c  = __hip_atomic_load(&pcnt[i / 16], __ATOMIC_RELAXED,
                                     __HIP_MEMORY_SCOPE_AGENT);
        out[i] = ps / fmaxf(c, 1.0f);
      }
    }
  }
}

// ---------------- launch ----------------
extern "C" void kernel_launch(void* const* d_in, const int* in_sizes, int n_in,
                              void* d_out, int out_size, void* d_ws, size_t ws_size,
                              hipStream_t stream)
{
  const float* x     = (const float*)d_in[0];
  const float* ef    = (const float*)d_in[1];
  const int*   et    = (const int*)d_in[2];
  const int*   esrc  = (const int*)d_in[3];
  const int*   edst  = (const int*)d_in[4];
  const int*   ctype = (const int*)d_in[5];
  const int*   bids  = (const int*)d_in[6];
  const float* emb1 = (const float*)d_in[8];
  const float* wh1  = (const float*)d_in[9];
  const float* bh1  = (const float*)d_in[10];
  const float* wg1  = (const float*)d_in[11];
  const float* bg1  = (const float*)d_in[12];
  const float* root1= (const float*)d_in[13];
  const float* bias1= (const float*)d_in[14];
  const float* emb2 = (const float*)d_in[15];
  const float* wh2  = (const float*)d_in[16];
  const float* bh2  = (const float*)d_in[17];
  const float* wg2  = (const float*)d_in[18];
  const float* bg2  = (const float*)d_in[19];
  const float* root2= (const float*)d_in[20];
  const float* bias2= (const float*)d_in[21];
  const float* emb3 = (const float*)d_in[22];
  const float* wh3  = (const float*)d_in[23];
  const float* bh3  = (const float*)d_in[24];
  const float* wg3  = (const float*)d_in[25];
  const float* bg3  = (const float*)d_in[26];
  const float* root3= (const float*)d_in[27];
  const float* bias3= (const float*)d_in[28];

  const int N = in_sizes[0] / IN1;
  const int E = in_sizes[2];
  const int B = out_size / OUT3;

  // workspace layout (16B-aligned sections)
  int4* edges   = (int4*)d_ws;                       // E recs
  int*  deg     = (int*)(edges + E);                 // N
  int*  pos     = deg + N;                           // E
  int*  row_ptr = pos + E;                           // N+1
  int*  bsum    = row_ptr + (N + 1);                 // <=64
  int*  done    = bsum + 64;                         // 1
  uintptr_t pp  = ((uintptr_t)(done + 4) + 15) & ~(uintptr_t)15;
  float4* P1    = (float4*)pp;                       // 25*D1
  float4* P2    = P1 + NTYPES * D1;                  // 25*D2
  float4* P3    = P2 + NTYPES * D2;                  // 25*D3
  float* h1     = (float*)(P3 + NTYPES * D3);        // N*HSTR
  float* h2     = h1 + (size_t)N * HSTR;             // N*HSTR
  float* psum   = h2 + (size_t)N * HSTR;             // B*16
  float* pcnt   = psum + (size_t)B * 16;             // B

  const int nChunk = (N + 1023) / 1024;

  init_kernel<<<128, 256, 0, stream>>>(
      emb1, wh1, bh1, wg1, bg1, emb2, wh2, bh2, wg2, bg2,
      emb3, wh3, bh3, wg3, bg3, P1, P2, P3, deg, N, psum, pcnt, done, B);
  hist_kernel<<<(E + 255) / 256, 256, 0, stream>>>(edst, deg, pos, E);
  scan_part_kernel<<<nChunk, 256, 0, stream>>>(deg, row_ptr, bsum, N);
  scan_add2_kernel<<<nChunk, 256, 0, stream>>>(row_ptr, bsum, N, nChunk);
  permute_kernel<<<(E + 255) / 256, 256, 0, stream>>>(
      edst, esrc, et, (const float2*)ef, row_ptr, pos, edges, E);

  const int g256 = (N + 15) / 16;     // 16 nodes per 256-thread block
  layer_kernel<IN1, HIDC, IN1, false, 256><<<g256, 256, 0, stream>>>(
      x, edges, row_ptr, P1, root1, bias1,
      h1, nullptr, nullptr, nullptr, nullptr, nullptr, N, B);
  layer_kernel<HIDC, HIDC, HSTR, false, 256><<<g256, 256, 0, stream>>>(
      h1, edges, row_ptr, P2, root2, bias2,
      h2, nullptr, nullptr, nullptr, nullptr, nullptr, N, B);

  const int g1024 = (N + 63) / 64;    // 64 nodes per 1024-thread block
  layer_kernel<HIDC, OUT3, HSTR, true, 1024><<<g1024, 1024, 0, stream>>>(
      h2, edges, row_ptr, P3, root3, bias3,
      psum, ctype, bids, pcnt, done, (float*)d_out, N, B);
}

// Round 11
// 426.097 us; speedup vs baseline: 1.6839x; 1.1584x over previous
//
#include <hip/hip_runtime.h>
#include <stdint.h>

#define IN1 16
#define HIDC 10
#define OUT3 16
#define NTYPES 25
#define MAXB 8
#define HSTR 12   // padded row stride (floats) for h1/h2: 48B, 16B-aligned rows

#define D1 (IN1 * HIDC)    // 160
#define D2 (HIDC * HIDC)   // 100
#define D3 (HIDC * OUT3)   // 160

// ---------------- init: prep P tables + zero deg/psum/pcnt/done --------------
// w_edge = relu(f0*P0 + f1*P1 + P2); P0=emb*wh0+wg0, P1=emb*wh1+wg1, P2=emb*bh+bg
__global__ __launch_bounds__(256) void init_kernel(
    const float* __restrict__ emb1, const float* __restrict__ wh1,
    const float* __restrict__ bh1, const float* __restrict__ wg1,
    const float* __restrict__ bg1,
    const float* __restrict__ emb2, const float* __restrict__ wh2,
    const float* __restrict__ bh2, const float* __restrict__ wg2,
    const float* __restrict__ bg2,
    const float* __restrict__ emb3, const float* __restrict__ wh3,
    const float* __restrict__ bh3, const float* __restrict__ wg3,
    const float* __restrict__ bg3,
    float4* __restrict__ P1, float4* __restrict__ P2, float4* __restrict__ P3,
    int* __restrict__ deg, int N,
    float* __restrict__ psum, float* __restrict__ pcnt,
    int* __restrict__ done, int B)
{
  int gtid = blockIdx.x * 256 + threadIdx.x;
  int gstr = gridDim.x * 256;
  const int nPrep = NTYPES * (D1 + D2 + D3);
  for (int i = gtid; i < nPrep; i += gstr) {
    const float *emb, *wh, *bh, *wg, *bg; float4* P; int D, k;
    if (i < NTYPES * D1) {
      emb = emb1; wh = wh1; bh = bh1; wg = wg1; bg = bg1; P = P1; D = D1; k = i;
    } else if (i < NTYPES * (D1 + D2)) {
      emb = emb2; wh = wh2; bh = bh2; wg = wg2; bg = bg2; P = P2; D = D2;
      k = i - NTYPES * D1;
    } else {
      emb = emb3; wh = wh3; bh = bh3; wg = wg3; bg = bg3; P = P3; D = D3;
      k = i - NTYPES * (D1 + D2);
    }
    int j = k - (k / D) * D;
    float e = emb[k];
    float4 p;
    p.x = fmaf(e, wh[j],     wg[j]);
    p.y = fmaf(e, wh[D + j], wg[D + j]);
    p.z = fmaf(e, bh[j],     bg[j]);
    p.w = 0.f;
    P[k] = p;
  }
  for (int i = gtid; i < N; i += gstr) deg[i] = 0;
  for (int i = gtid; i < B * 16; i += gstr) psum[i] = 0.f;
  for (int i = gtid; i < B; i += gstr) pcnt[i] = 0.f;
  if (gtid == 0) *done = 0;
}

// ---------------- histogram + within-bucket rank (1 atomic per edge) ----------
__global__ __launch_bounds__(256) void hist_kernel(const int* __restrict__ edst,
                                                   int* __restrict__ deg,
                                                   int* __restrict__ pos, int E) {
  int e = blockIdx.x * blockDim.x + threadIdx.x;
  if (e < E) pos[e] = atomicAdd(&deg[edst[e]], 1);
}

// ---------------- per-1024-chunk local scan + chunk sum ----------------------
__global__ __launch_bounds__(256) void scan_part_kernel(const int* __restrict__ deg,
                                                        int* __restrict__ row_ptr,
                                                        int* __restrict__ bsum, int N) {
  __shared__ int wsums[4];
  int tid = threadIdx.x, lane = tid & 63, wid = tid >> 6;
  int idx0 = (blockIdx.x * 256 + tid) * 4;
  int4 v = make_int4(0, 0, 0, 0);
  if (idx0 < N)     v.x = deg[idx0];
  if (idx0 + 1 < N) v.y = deg[idx0 + 1];
  if (idx0 + 2 < N) v.z = deg[idx0 + 2];
  if (idx0 + 3 < N) v.w = deg[idx0 + 3];
  int s = v.x + v.y + v.z + v.w;
  int x = s;
  #pragma unroll
  for (int off = 1; off < 64; off <<= 1) {
    int y = __shfl_up(x, off);
    if (lane >= off) x += y;
  }
  if (lane == 63) wsums[wid] = x;
  __syncthreads();
  int wpre = 0;
  #pragma unroll
  for (int w = 0; w < 4; ++w) if (w < wid) wpre += wsums[w];
  int excl = x - s + wpre;
  if (idx0 < N)     row_ptr[idx0]     = excl;
  if (idx0 + 1 < N) row_ptr[idx0 + 1] = excl + v.x;
  if (idx0 + 2 < N) row_ptr[idx0 + 2] = excl + v.x + v.y;
  if (idx0 + 3 < N) row_ptr[idx0 + 3] = excl + v.x + v.y + v.z;
  if (tid == 255) bsum[blockIdx.x] = excl + s;
}

// ---------------- fused chunk-offset scan + add (chunks <= 64) ----------------
__global__ __launch_bounds__(256) void scan_add2_kernel(int* __restrict__ row_ptr,
                                                        const int* __restrict__ bsum,
                                                        int N, int chunks) {
  __shared__ int s_off;
  int c = blockIdx.x, tid = threadIdx.x;
  if (tid < 64) {
    int v = (tid < c) ? bsum[tid] : 0;
    #pragma unroll
    for (int off = 32; off >= 1; off >>= 1) v += __shfl_xor(v, off);
    if (tid == 0) s_off = v;
  }
  __syncthreads();
  int off = s_off;
  int base = c * 1024 + tid * 4;
  #pragma unroll
  for (int j = 0; j < 4; ++j) {
    int idx = base + j;
    if (idx < N) row_ptr[idx] += off;
  }
  if (c == chunks - 1 && tid == 0) row_ptr[N] = off + bsum[c];
}

// ---------------- scatter edges into CSR order (plain stores) ----------------
__global__ __launch_bounds__(256) void permute_kernel(
    const int* __restrict__ edst, const int* __restrict__ esrc,
    const int* __restrict__ et, const float2* __restrict__ ef,
    const int* __restrict__ row_ptr, const int* __restrict__ pos,
    int4* __restrict__ edges, int E) {
  int e = blockIdx.x * blockDim.x + threadIdx.x;
  if (e >= E) return;
  int d = edst[e];
  int idx = row_ptr[d] + pos[e];
  float2 f = ef[e];
  int4 r;
  r.x = esrc[e];
  r.y = et[e];
  r.z = __float_as_int(f.x);
  r.w = __float_as_int(f.y);
  edges[idx] = r;
}

// ---------------- fused gather layer (R8-exact inner loop + LDS s_P) ---------
// Per (i,oc): 1 broadcast ds_read_b128 of packed {P0,P1,P2} + 4 VALU.
// TSTR = D+1 (layout kept from R7/R8).  POOL variant folds finalize via a
// device-scope done-counter (verified in R10).
template<int IN_C, int O, int XS, bool POOL, int BS>
__global__ __launch_bounds__(BS) void layer_kernel(
    const float* __restrict__ xin,      // [N, XS]
    const int4* __restrict__ edges,     // CSR by dst: {src, type, f0, f1}
    const int* __restrict__ row_ptr,    // [N+1]
    const float4* __restrict__ Pg,      // [25*D] packed {P0,P1,P2,-}
    const float* __restrict__ root,     // [IN_C, O]
    const float* __restrict__ bias,     // [O]
    float* __restrict__ hout,           // [N, HSTR], or psum[B*16] if POOL
    const int* __restrict__ ctype, const int* __restrict__ bids,
    float* __restrict__ pcnt,           // [B] (POOL only)
    int* __restrict__ done,             // (POOL only)
    float* __restrict__ out,            // [B*16] (POOL only)
    int N, int B)
{
  constexpr int D = IN_C * O;
  constexpr int TSTR = D + 1;
  constexpr int NPB = BS / 16;
  __shared__ float4 s_P[NTYPES * TSTR];
  __shared__ float s_psum[POOL ? (MAXB * 16) : 1];
  __shared__ float s_pcnt[POOL ? MAXB : 1];

  int tid = threadIdx.x;
  for (int k = tid; k < NTYPES * D; k += BS) {
    int t = k / D, j = k - t * D;
    s_P[t * TSTR + j] = Pg[k];
  }
  if (POOL) {
    for (int i = tid; i < MAXB * 16; i += BS) s_psum[i] = 0.f;
    for (int i = tid; i < MAXB; i += BS) s_pcnt[i] = 0.f;
  }
  __syncthreads();

  int nl = tid >> 4;
  int o = tid & 15;
  int oc = (O == 16) ? o : ((o < O) ? o : 0);
  int n = blockIdx.x * NPB + nl;

  float acc = 0.f;
  int start = 0, end = 0;
  if (n < N) { start = row_ptr[n]; end = row_ptr[n + 1]; }
  for (int e = start; e < end; ++e) {
    int4 r = edges[e];
    float f0 = __int_as_float(r.z), f1 = __int_as_float(r.w);
    const float4* __restrict__ pb = s_P + r.y * TSTR + oc;
    const float* __restrict__ xr = xin + (size_t)r.x * XS;
    #pragma unroll
    for (int q = 0; q < IN_C / 4; ++q) {
      float4 xq = ((const float4*)xr)[q];
      float4 p0 = pb[(4 * q + 0) * O];
      float4 p1 = pb[(4 * q + 1) * O];
      float4 p2 = pb[(4 * q + 2) * O];
      float4 p3 = pb[(4 * q + 3) * O];
      acc = fmaf(xq.x, fmaxf(fmaf(f0, p0.x, fmaf(f1, p0.y, p0.z)), 0.f), acc);
      acc = fmaf(xq.y, fmaxf(fmaf(f0, p1.x, fmaf(f1, p1.y, p1.z)), 0.f), acc);
      acc = fmaf(xq.z, fmaxf(fmaf(f0, p2.x, fmaf(f1, p2.y, p2.z)), 0.f), acc);
      acc = fmaf(xq.w, fmaxf(fmaf(f0, p3.x, fmaf(f1, p3.y, p3.z)), 0.f), acc);
    }
    if constexpr (IN_C % 4 == 2) {
      float2 xq = ((const float2*)xr)[IN_C / 2 - 1];
      float4 p0 = pb[(IN_C - 2) * O];
      float4 p1 = pb[(IN_C - 1) * O];
      acc = fmaf(xq.x, fmaxf(fmaf(f0, p0.x, fmaf(f1, p0.y, p0.z)), 0.f), acc);
      acc = fmaf(xq.y, fmaxf(fmaf(f0, p1.x, fmaf(f1, p1.y, p1.z)), 0.f), acc);
    }
  }

  if (n < N && o < O) {
    float inv = 1.0f / fmaxf((float)(end - start), 1.0f);
    float v = fmaf(acc, inv, bias[o]);
    const float* __restrict__ xr = xin + (size_t)n * XS;
    #pragma unroll
    for (int i = 0; i < IN_C; ++i) v = fmaf(xr[i], root[i * O + o], v);
    v = fmaxf(v, 0.f);
    if (!POOL) {
      hout[(size_t)n * HSTR + o] = v;
    } else {
      if (ctype[n] == 1) {
        int b = bids[n];
        atomicAdd(&s_psum[b * 16 + o], v);
        if (o == 0) atomicAdd(&s_pcnt[b], 1.0f);
      }
    }
  }

  if (POOL) {
    __syncthreads();
    for (int i = tid; i < B * 16; i += BS) {
      float v = s_psum[i];
      if (v != 0.f) atomicAdd(&hout[i], v);    // hout = psum (global)
    }
    for (int i = tid; i < B; i += BS) {
      float c = s_pcnt[i];
      if (c != 0.f) atomicAdd(&pcnt[i], c);
    }
    // folded finalize: last block to finish divides and writes out
    __threadfence();
    __shared__ int s_last;
    if (tid == 0) s_last = (atomicAdd(done, 1) == (int)gridDim.x - 1) ? 1 : 0;
    __syncthreads();
    if (s_last) {
      for (int i = tid; i < B * 16; i += BS) {
        float ps = __hip_atomic_load(&hout[i], __ATOMIC_RELAXED,
                                     __HIP_MEMORY_SCOPE_AGENT);
        float c  = __hip_atomic_load(&pcnt[i / 16], __ATOMIC_RELAXED,
                                     __HIP_MEMORY_SCOPE_AGENT);
        out[i] = ps / fmaxf(c, 1.0f);
      }
    }
  }
}

// ---------------- launch ----------------
extern "C" void kernel_launch(void* const* d_in, const int* in_sizes, int n_in,
                              void* d_out, int out_size, void* d_ws, size_t ws_size,
                              hipStream_t stream)
{
  const float* x     = (const float*)d_in[0];
  const float* ef    = (const float*)d_in[1];
  const int*   et    = (const int*)d_in[2];
  const int*   esrc  = (const int*)d_in[3];
  const int*   edst  = (const int*)d_in[4];
  const int*   ctype = (const int*)d_in[5];
  const int*   bids  = (const int*)d_in[6];
  const float* emb1 = (const float*)d_in[8];
  const float* wh1  = (const float*)d_in[9];
  const float* bh1  = (const float*)d_in[10];
  const float* wg1  = (const float*)d_in[11];
  const float* bg1  = (const float*)d_in[12];
  const float* root1= (const float*)d_in[13];
  const float* bias1= (const float*)d_in[14];
  const float* emb2 = (const float*)d_in[15];
  const float* wh2  = (const float*)d_in[16];
  const float* bh2  = (const float*)d_in[17];
  const float* wg2  = (const float*)d_in[18];
  const float* bg2  = (const float*)d_in[19];
  const float* root2= (const float*)d_in[20];
  const float* bias2= (const float*)d_in[21];
  const float* emb3 = (const float*)d_in[22];
  const float* wh3  = (const float*)d_in[23];
  const float* bh3  = (const float*)d_in[24];
  const float* wg3  = (const float*)d_in[25];
  const float* bg3  = (const float*)d_in[26];
  const float* root3= (const float*)d_in[27];
  const float* bias3= (const float*)d_in[28];

  const int N = in_sizes[0] / IN1;
  const int E = in_sizes[2];
  const int B = out_size / OUT3;

  // workspace layout (16B-aligned sections)
  int4* edges   = (int4*)d_ws;                       // E recs
  int*  deg     = (int*)(edges + E);                 // N
  int*  pos     = deg + N;                           // E
  int*  row_ptr = pos + E;                           // N+1
  int*  bsum    = row_ptr + (N + 1);                 // <=64
  int*  done    = bsum + 64;                         // 1 (+3 pad)
  uintptr_t pp  = ((uintptr_t)(done + 4) + 15) & ~(uintptr_t)15;
  float4* P1    = (float4*)pp;                       // 25*D1
  float4* P2    = P1 + NTYPES * D1;                  // 25*D2
  float4* P3    = P2 + NTYPES * D2;                  // 25*D3
  float* h1     = (float*)(P3 + NTYPES * D3);        // N*HSTR
  float* h2     = h1 + (size_t)N * HSTR;             // N*HSTR
  float* psum   = h2 + (size_t)N * HSTR;             // B*16
  float* pcnt   = psum + (size_t)B * 16;             // B

  const int nChunk = (N + 1023) / 1024;

  init_kernel<<<128, 256, 0, stream>>>(
      emb1, wh1, bh1, wg1, bg1, emb2, wh2, bh2, wg2, bg2,
      emb3, wh3, bh3, wg3, bg3, P1, P2, P3, deg, N, psum, pcnt, done, B);
  hist_kernel<<<(E + 255) / 256, 256, 0, stream>>>(edst, deg, pos, E);
  scan_part_kernel<<<nChunk, 256, 0, stream>>>(deg, row_ptr, bsum, N);
  scan_add2_kernel<<<nChunk, 256, 0, stream>>>(row_ptr, bsum, N, nChunk);
  permute_kernel<<<(E + 255) / 256, 256, 0, stream>>>(
      edst, esrc, et, (const float2*)ef, row_ptr, pos, edges, E);

  const int g512 = (N + 31) / 32;     // 32 nodes per 512-thread block
  layer_kernel<IN1, HIDC, IN1, false, 512><<<g512, 512, 0, stream>>>(
      x, edges, row_ptr, P1, root1, bias1,
      h1, nullptr, nullptr, nullptr, nullptr, nullptr, N, B);
  layer_kernel<HIDC, HIDC, HSTR, false, 512><<<g512, 512, 0, stream>>>(
      h1, edges, row_ptr, P2, root2, bias2,
      h2, nullptr, nullptr, nullptr, nullptr, nullptr, N, B);

  const int g1024 = (N + 63) / 64;    // 64 nodes per 1024-thread block
  layer_kernel<HIDC, OUT3, HSTR, true, 1024><<<g1024, 1024, 0, stream>>>(
      h2, edges, row_ptr, P3, root3, bias3,
      psum, ctype, bids, pcnt, done, (float*)d_out, N, B);
}

// Round 12
// 253.957 us; speedup vs baseline: 2.8252x; 1.6778x over previous
//
#include <hip/hip_runtime.h>
#include <stdint.h>

#define IN1 16
#define HIDC 10
#define OUT3 16
#define NTYPES 25
#define MAXB 8
#define HSTR 12   // padded row stride (floats) for h1/h2: 48B, 16B-aligned rows

#define D1 (IN1 * HIDC)    // 160
#define D2 (HIDC * HIDC)   // 100
#define D3 (HIDC * OUT3)   // 160

// ---------------- init: prep P tables + zero deg/psum/pcnt -------------------
// w_edge = relu(f0*P0 + f1*P1 + P2); P0=emb*wh0+wg0, P1=emb*wh1+wg1, P2=emb*bh+bg
__global__ __launch_bounds__(256) void init_kernel(
    const float* __restrict__ emb1, const float* __restrict__ wh1,
    const float* __restrict__ bh1, const float* __restrict__ wg1,
    const float* __restrict__ bg1,
    const float* __restrict__ emb2, const float* __restrict__ wh2,
    const float* __restrict__ bh2, const float* __restrict__ wg2,
    const float* __restrict__ bg2,
    const float* __restrict__ emb3, const float* __restrict__ wh3,
    const float* __restrict__ bh3, const float* __restrict__ wg3,
    const float* __restrict__ bg3,
    float4* __restrict__ P1, float4* __restrict__ P2, float4* __restrict__ P3,
    int* __restrict__ deg, int N,
    float* __restrict__ psum, float* __restrict__ pcnt, int B)
{
  int gtid = blockIdx.x * 256 + threadIdx.x;
  int gstr = gridDim.x * 256;
  const int nPrep = NTYPES * (D1 + D2 + D3);
  for (int i = gtid; i < nPrep; i += gstr) {
    const float *emb, *wh, *bh, *wg, *bg; float4* P; int D, k;
    if (i < NTYPES * D1) {
      emb = emb1; wh = wh1; bh = bh1; wg = wg1; bg = bg1; P = P1; D = D1; k = i;
    } else if (i < NTYPES * (D1 + D2)) {
      emb = emb2; wh = wh2; bh = bh2; wg = wg2; bg = bg2; P = P2; D = D2;
      k = i - NTYPES * D1;
    } else {
      emb = emb3; wh = wh3; bh = bh3; wg = wg3; bg = bg3; P = P3; D = D3;
      k = i - NTYPES * (D1 + D2);
    }
    int j = k - (k / D) * D;
    float e = emb[k];
    float4 p;
    p.x = fmaf(e, wh[j],     wg[j]);
    p.y = fmaf(e, wh[D + j], wg[D + j]);
    p.z = fmaf(e, bh[j],     bg[j]);
    p.w = 0.f;
    P[k] = p;
  }
  for (int i = gtid; i < N; i += gstr) deg[i] = 0;
  for (int i = gtid; i < B * 16; i += gstr) psum[i] = 0.f;
  for (int i = gtid; i < B; i += gstr) pcnt[i] = 0.f;
}

// ---------------- histogram + within-bucket rank (1 atomic per edge) ----------
__global__ __launch_bounds__(256) void hist_kernel(const int* __restrict__ edst,
                                                   int* __restrict__ deg,
                                                   int* __restrict__ pos, int E) {
  int e = blockIdx.x * blockDim.x + threadIdx.x;
  if (e < E) pos[e] = atomicAdd(&deg[edst[e]], 1);
}

// ---------------- per-1024-chunk local scan + chunk sum ----------------------
__global__ __launch_bounds__(256) void scan_part_kernel(const int* __restrict__ deg,
                                                        int* __restrict__ row_ptr,
                                                        int* __restrict__ bsum, int N) {
  __shared__ int wsums[4];
  int tid = threadIdx.x, lane = tid & 63, wid = tid >> 6;
  int idx0 = (blockIdx.x * 256 + tid) * 4;
  int4 v = make_int4(0, 0, 0, 0);
  if (idx0 < N)     v.x = deg[idx0];
  if (idx0 + 1 < N) v.y = deg[idx0 + 1];
  if (idx0 + 2 < N) v.z = deg[idx0 + 2];
  if (idx0 + 3 < N) v.w = deg[idx0 + 3];
  int s = v.x + v.y + v.z + v.w;
  int x = s;
  #pragma unroll
  for (int off = 1; off < 64; off <<= 1) {
    int y = __shfl_up(x, off);
    if (lane >= off) x += y;
  }
  if (lane == 63) wsums[wid] = x;
  __syncthreads();
  int wpre = 0;
  #pragma unroll
  for (int w = 0; w < 4; ++w) if (w < wid) wpre += wsums[w];
  int excl = x - s + wpre;
  if (idx0 < N)     row_ptr[idx0]     = excl;
  if (idx0 + 1 < N) row_ptr[idx0 + 1] = excl + v.x;
  if (idx0 + 2 < N) row_ptr[idx0 + 2] = excl + v.x + v.y;
  if (idx0 + 3 < N) row_ptr[idx0 + 3] = excl + v.x + v.y + v.z;
  if (tid == 255) bsum[blockIdx.x] = excl + s;
}

// ---------------- fused chunk-offset scan + add (chunks <= 64) ----------------
__global__ __launch_bounds__(256) void scan_add2_kernel(int* __restrict__ row_ptr,
                                                        const int* __restrict__ bsum,
                                                        int N, int chunks) {
  __shared__ int s_off;
  int c = blockIdx.x, tid = threadIdx.x;
  if (tid < 64) {
    int v = (tid < c) ? bsum[tid] : 0;
    #pragma unroll
    for (int off = 32; off >= 1; off >>= 1) v += __shfl_xor(v, off);
    if (tid == 0) s_off = v;
  }
  __syncthreads();
  int off = s_off;
  int base = c * 1024 + tid * 4;
  #pragma unroll
  for (int j = 0; j < 4; ++j) {
    int idx = base + j;
    if (idx < N) row_ptr[idx] += off;
  }
  if (c == chunks - 1 && tid == 0) row_ptr[N] = off + bsum[c];
}

// ---------------- scatter edges into CSR order (plain stores) ----------------
__global__ __launch_bounds__(256) void permute_kernel(
    const int* __restrict__ edst, const int* __restrict__ esrc,
    const int* __restrict__ et, const float2* __restrict__ ef,
    const int* __restrict__ row_ptr, const int* __restrict__ pos,
    int4* __restrict__ edges, int E) {
  int e = blockIdx.x * blockDim.x + threadIdx.x;
  if (e >= E) return;
  int d = edst[e];
  int idx = row_ptr[d] + pos[e];
  float2 f = ef[e];
  int4 r;
  r.x = esrc[e];
  r.y = et[e];
  r.z = __float_as_int(f.x);
  r.w = __float_as_int(f.y);
  edges[idx] = r;
}

// ---------------- fused gather layer (R8 byte-exact) -------------------------
// Per (i,oc): 1 broadcast ds_read_b128 of packed {P0,P1,P2} + 4 VALU.
// TSTR = D+1.  NO folded finalize: the R11 tail fold perturbed regalloc
// (52 -> 36 VGPR) and serialized the load pipeline (218 us vs ~42 us).
template<int IN_C, int O, int XS, bool POOL, int BS>
__global__ __launch_bounds__(BS) void layer_kernel(
    const float* __restrict__ xin, const int4* __restrict__ edges,
    const int* __restrict__ row_ptr, const float4* __restrict__ Pg,
    const float* __restrict__ root, const float* __restrict__ bias,
    float* __restrict__ hout, const int* __restrict__ ctype,
    const int* __restrict__ bids, float* __restrict__ pcnt, int N, int B)
{
  constexpr int D = IN_C * O;
  constexpr int TSTR = D + 1;
  constexpr int NPB = BS / 16;
  __shared__ float4 s_P[NTYPES * TSTR];
  __shared__ float s_psum[POOL ? (MAXB * 16) : 1];
  __shared__ float s_pcnt[POOL ? MAXB : 1];

  int tid = threadIdx.x;
  for (int k = tid; k < NTYPES * D; k += BS) {
    int t = k / D, j = k - t * D;
    s_P[t * TSTR + j] = Pg[k];
  }
  if (POOL) {
    for (int i = tid; i < MAXB * 16; i += BS) s_psum[i] = 0.f;
    for (int i = tid; i < MAXB; i += BS) s_pcnt[i] = 0.f;
  }
  __syncthreads();

  int nl = tid >> 4;
  int o = tid & 15;
  int oc = (O == 16) ? o : ((o < O) ? o : 0);
  int n = blockIdx.x * NPB + nl;

  float acc = 0.f;
  int start = 0, end = 0;
  if (n < N) { start = row_ptr[n]; end = row_ptr[n + 1]; }
  for (int e = start; e < end; ++e) {
    int4 r = edges[e];
    float f0 = __int_as_float(r.z), f1 = __int_as_float(r.w);
    const float4* __restrict__ pb = s_P + r.y * TSTR + oc;
    const float* __restrict__ xr = xin + (size_t)r.x * XS;
    #pragma unroll
    for (int q = 0; q < IN_C / 4; ++q) {
      float4 xq = ((const float4*)xr)[q];
      float4 p0 = pb[(4 * q + 0) * O];
      float4 p1 = pb[(4 * q + 1) * O];
      float4 p2 = pb[(4 * q + 2) * O];
      float4 p3 = pb[(4 * q + 3) * O];
      acc = fmaf(xq.x, fmaxf(fmaf(f0, p0.x, fmaf(f1, p0.y, p0.z)), 0.f), acc);
      acc = fmaf(xq.y, fmaxf(fmaf(f0, p1.x, fmaf(f1, p1.y, p1.z)), 0.f), acc);
      acc = fmaf(xq.z, fmaxf(fmaf(f0, p2.x, fmaf(f1, p2.y, p2.z)), 0.f), acc);
      acc = fmaf(xq.w, fmaxf(fmaf(f0, p3.x, fmaf(f1, p3.y, p3.z)), 0.f), acc);
    }
    if constexpr (IN_C % 4 == 2) {
      float2 xq = ((const float2*)xr)[IN_C / 2 - 1];
      float4 p0 = pb[(IN_C - 2) * O];
      float4 p1 = pb[(IN_C - 1) * O];
      acc = fmaf(xq.x, fmaxf(fmaf(f0, p0.x, fmaf(f1, p0.y, p0.z)), 0.f), acc);
      acc = fmaf(xq.y, fmaxf(fmaf(f0, p1.x, fmaf(f1, p1.y, p1.z)), 0.f), acc);
    }
  }

  if (n < N && o < O) {
    float inv = 1.0f / fmaxf((float)(end - start), 1.0f);
    float v = fmaf(acc, inv, bias[o]);
    const float* __restrict__ xr = xin + (size_t)n * XS;
    #pragma unroll
    for (int i = 0; i < IN_C; ++i) v = fmaf(xr[i], root[i * O + o], v);
    v = fmaxf(v, 0.f);
    if (!POOL) {
      hout[(size_t)n * HSTR + o] = v;
    } else {
      if (ctype[n] == 1) {
        int b = bids[n];
        atomicAdd(&s_psum[b * 16 + o], v);
        if (o == 0) atomicAdd(&s_pcnt[b], 1.0f);
      }
    }
  }

  if (POOL) {
    __syncthreads();
    for (int i = tid; i < B * 16; i += BS) {
      float v = s_psum[i];
      if (v != 0.f) atomicAdd(&hout[i], v);
    }
    for (int i = tid; i < B; i += BS) {
      float c = s_pcnt[i];
      if (c != 0.f) atomicAdd(&pcnt[i], c);
    }
  }
}

__global__ __launch_bounds__(256) void finalize_kernel(
    const float* __restrict__ psum, const float* __restrict__ pcnt,
    float* __restrict__ out, int B) {
  int i = blockIdx.x * blockDim.x + threadIdx.x;
  if (i >= B * OUT3) return;
  int b = i / OUT3;
  out[i] = psum[i] / fmaxf(pcnt[b], 1.0f);
}

// ---------------- launch ----------------
extern "C" void kernel_launch(void* const* d_in, const int* in_sizes, int n_in,
                              void* d_out, int out_size, void* d_ws, size_t ws_size,
                              hipStream_t stream)
{
  const float* x     = (const float*)d_in[0];
  const float* ef    = (const float*)d_in[1];
  const int*   et    = (const int*)d_in[2];
  const int*   esrc  = (const int*)d_in[3];
  const int*   edst  = (const int*)d_in[4];
  const int*   ctype = (const int*)d_in[5];
  const int*   bids  = (const int*)d_in[6];
  const float* emb1 = (const float*)d_in[8];
  const float* wh1  = (const float*)d_in[9];
  const float* bh1  = (const float*)d_in[10];
  const float* wg1  = (const float*)d_in[11];
  const float* bg1  = (const float*)d_in[12];
  const float* root1= (const float*)d_in[13];
  const float* bias1= (const float*)d_in[14];
  const float* emb2 = (const float*)d_in[15];
  const float* wh2  = (const float*)d_in[16];
  const float* bh2  = (const float*)d_in[17];
  const float* wg2  = (const float*)d_in[18];
  const float* bg2  = (const float*)d_in[19];
  const float* root2= (const float*)d_in[20];
  const float* bias2= (const float*)d_in[21];
  const float* emb3 = (const float*)d_in[22];
  const float* wh3  = (const float*)d_in[23];
  const float* bh3  = (const float*)d_in[24];
  const float* wg3  = (const float*)d_in[25];
  const float* bg3  = (const float*)d_in[26];
  const float* root3= (const float*)d_in[27];
  const float* bias3= (const float*)d_in[28];

  const int N = in_sizes[0] / IN1;
  const int E = in_sizes[2];
  const int B = out_size / OUT3;

  // workspace layout (16B-aligned sections)
  int4* edges   = (int4*)d_ws;                       // E recs
  int*  deg     = (int*)(edges + E);                 // N
  int*  pos     = deg + N;                           // E
  int*  row_ptr = pos + E;                           // N+1
  int*  bsum    = row_ptr + (N + 1);                 // <=64
  uintptr_t pp  = ((uintptr_t)(bsum + 64) + 15) & ~(uintptr_t)15;
  float4* P1    = (float4*)pp;                       // 25*D1
  float4* P2    = P1 + NTYPES * D1;                  // 25*D2
  float4* P3    = P2 + NTYPES * D2;                  // 25*D3
  float* h1     = (float*)(P3 + NTYPES * D3);        // N*HSTR
  float* h2     = h1 + (size_t)N * HSTR;             // N*HSTR
  float* psum   = h2 + (size_t)N * HSTR;             // B*16
  float* pcnt   = psum + (size_t)B * 16;             // B

  const int nChunk = (N + 1023) / 1024;

  init_kernel<<<128, 256, 0, stream>>>(
      emb1, wh1, bh1, wg1, bg1, emb2, wh2, bh2, wg2, bg2,
      emb3, wh3, bh3, wg3, bg3, P1, P2, P3, deg, N, psum, pcnt, B);
  hist_kernel<<<(E + 255) / 256, 256, 0, stream>>>(edst, deg, pos, E);
  scan_part_kernel<<<nChunk, 256, 0, stream>>>(deg, row_ptr, bsum, N);
  scan_add2_kernel<<<nChunk, 256, 0, stream>>>(row_ptr, bsum, N, nChunk);
  permute_kernel<<<(E + 255) / 256, 256, 0, stream>>>(
      edst, esrc, et, (const float2*)ef, row_ptr, pos, edges, E);

  const int g512 = (N + 31) / 32;     // 32 nodes per 512-thread block
  layer_kernel<IN1, HIDC, IN1, false, 512><<<g512, 512, 0, stream>>>(
      x, edges, row_ptr, P1, root1, bias1,
      h1, nullptr, nullptr, nullptr, N, B);
  layer_kernel<HIDC, HIDC, HSTR, false, 512><<<g512, 512, 0, stream>>>(
      h1, edges, row_ptr, P2, root2, bias2,
      h2, nullptr, nullptr, nullptr, N, B);

  const int g1024 = (N + 63) / 64;    // 64 nodes per 1024-thread block
  layer_kernel<HIDC, OUT3, HSTR, true, 1024><<<g1024, 1024, 0, stream>>>(
      h2, edges, row_ptr, P3, root3, bias3,
      psum, ctype, bids, pcnt, N, B);

  finalize_kernel<<<1, 256, 0, stream>>>(psum, pcnt, (float*)d_out, B);
}